// Round 12
// baseline (424.504 us; speedup 1.0000x reference)
//
#include <hip/hip_runtime.h>
#include <hip/hip_bf16.h>
#include <math.h>

#define H_    16
#define KV_   8
#define D_    128
#define HID_  2048
#define NQKV_ 4096   // H*D + KV*D + KV*D
#define SCALE_ 0.08838834764831845f   // 128^-0.5

typedef __attribute__((ext_vector_type(8))) short bf16x8;
typedef __attribute__((ext_vector_type(4))) float f32x4;
typedef __attribute__((ext_vector_type(4))) short short4v;

__device__ inline unsigned short f2bf(float f) {
  unsigned u = __builtin_bit_cast(unsigned, f);
  u += 0x7FFF + ((u >> 16) & 1);   // RNE
  return (unsigned short)(u >> 16);
}

#define GLDS16(g, l)                                                     \
  __builtin_amdgcn_global_load_lds(                                      \
      (const __attribute__((address_space(1))) void*)(g),                \
      (__attribute__((address_space(3))) void*)(l), 16, 0, 0)

// ======== merged prep: x->bf16 | Wq/Wk/Wv transpose->wT | Wo transpose->wTo ========
// grid: [0,4096) x-convert, [4096,12288) qkv transpose, [12288,16384) Wo transpose
__global__ __launch_bounds__(256) void prep_all(
    const float* __restrict__ x, unsigned short* __restrict__ xb,
    const float* __restrict__ Wq, const float* __restrict__ Wk,
    const float* __restrict__ Wv, unsigned short* __restrict__ wT,
    const float* __restrict__ Wo, unsigned short* __restrict__ wTo) {
  const int bid = blockIdx.x;
  if (bid < 4096) {                     // ---- x -> bf16, x8 per thread ----
    const int i = bid * 256 + threadIdx.x;
    const float4* p = (const float4*)x + (size_t)i * 2;
    float4 a = p[0], b = p[1];
    unsigned short o[8] = {f2bf(a.x), f2bf(a.y), f2bf(a.z), f2bf(a.w),
                           f2bf(b.x), f2bf(b.y), f2bf(b.z), f2bf(b.w)};
    *(bf16x8*)(xb + (size_t)i * 8) = *(bf16x8*)o;
    return;
  }
  __shared__ float t[32][33];
  const int r = threadIdx.x >> 3, c4 = (threadIdx.x & 7) * 4;
  if (bid < 12288) {                    // ---- QKV weights -> wT (N=4096, K=2048) ----
    const int b2 = bid - 4096;
    const int n0 = (b2 & 127) * 32;     // 128 n-tiles
    const int k0 = (b2 >> 7) * 32;      // 64 k-tiles
    const float* src; int N, nloc;
    if (n0 < H_ * D_)                  { src = Wq; N = H_ * D_;  nloc = n0; }
    else if (n0 < H_ * D_ + KV_ * D_)  { src = Wk; N = KV_ * D_; nloc = n0 - H_ * D_; }
    else                               { src = Wv; N = KV_ * D_; nloc = n0 - H_ * D_ - KV_ * D_; }
    float4 v = *(const float4*)(src + (size_t)(k0 + r) * N + nloc + c4);
    t[r][c4 + 0] = v.x; t[r][c4 + 1] = v.y; t[r][c4 + 2] = v.z; t[r][c4 + 3] = v.w;
    __syncthreads();
    unsigned short o[4];
#pragma unroll
    for (int j = 0; j < 4; ++j) o[j] = f2bf(t[c4 + j][r]);
    *(short4v*)(wT + (size_t)(n0 + r) * HID_ + k0 + c4) = *(short4v*)o;
  } else {                              // ---- Wo transpose -> wTo (N=2048, K=2048) ----
    const int b3 = bid - 12288;
    const int n0 = (b3 & 63) * 32;      // 64 n-tiles
    const int k0 = (b3 >> 6) * 32;      // 64 k-tiles
    float4 v = *(const float4*)(Wo + (size_t)(k0 + r) * HID_ + n0 + c4);
    t[r][c4 + 0] = v.x; t[r][c4 + 1] = v.y; t[r][c4 + 2] = v.z; t[r][c4 + 3] = v.w;
    __syncthreads();
    unsigned short o[4];
#pragma unroll
    for (int j = 0; j < 4; ++j) o[j] = f2bf(t[c4 + j][r]);
    *(short4v*)(wTo + (size_t)(n0 + r) * (H_ * D_) + k0 + c4) = *(short4v*)o;
  }
}

// ======== 256x256x64 bf16 MFMA GEMM, 8 waves, LDS double-buffer, counted vmcnt ========
// (r10-proven, incl. T1 XCD swizzle)
#define QBM 256
#define QBN 256
#define QBK 64

template <int EPI>
__global__ __launch_bounds__(512, 2) void gemm256(
    const unsigned short* __restrict__ A,   // M x K row-major
    const unsigned short* __restrict__ Bt,  // N x K row-major
    float* __restrict__ C0, float* __restrict__ C1,
    unsigned short* __restrict__ C2, int M, int N, int K, int S) {
  __shared__ unsigned short As[2][QBM * QBK];
  __shared__ unsigned short Bs[2][QBN * QBK];
  const int tid = threadIdx.x;
  const int w = tid >> 6, lane = tid & 63;
  const int wm = w >> 2, wn = w & 3;
  const int fr = lane & 15, fq = lane >> 4;
  const int nwg = gridDim.x * gridDim.y;
  const int bid0 = blockIdx.y * gridDim.x + blockIdx.x;
  const int bid = (bid0 & 7) * (nwg >> 3) + (bid0 >> 3);
  const int bx = bid % gridDim.x, by = bid / gridDim.x;
  const int row0 = by * QBM, col0 = bx * QBN;

  const unsigned short* Ab = A + (size_t)row0 * K;
  const unsigned short* Bb = Bt + (size_t)col0 * K;
  const int srow = w * 8 + (lane >> 3);
  const int sc   = lane & 7;
  const int nt   = K / QBK;

  f32x4 acc[8][4] = {};

#define STAGE256(t_, buf_)                                                      \
  {                                                                             \
    const int k0_ = (t_) * QBK;                                                 \
    _Pragma("unroll")                                                           \
    for (int p = 0; p < 4; ++p) {                                               \
      const int r_ = p * 64 + srow;                                             \
      const int gc_ = sc ^ (r_ & 7);                                            \
      GLDS16(Ab + (size_t)r_ * K + k0_ + gc_ * 8,                               \
             &As[buf_][(p * 64 + w * 8) * QBK]);                                \
      GLDS16(Bb + (size_t)r_ * K + k0_ + gc_ * 8,                               \
             &Bs[buf_][(p * 64 + w * 8) * QBK]);                                \
    }                                                                           \
  }

  STAGE256(0, 0);
  STAGE256(1, 1);
  asm volatile("s_waitcnt vmcnt(8)" ::: "memory");
  __builtin_amdgcn_s_barrier();
  __builtin_amdgcn_sched_barrier(0);

  for (int t = 0; t < nt; ++t) {
    const int buf = t & 1;
    __builtin_amdgcn_s_setprio(1);
#pragma unroll
    for (int s = 0; s < 2; ++s) {
      bf16x8 af[8], bf[4];
#pragma unroll
      for (int i = 0; i < 8; ++i) {
        const int r = wm * 128 + i * 16 + fr;
        af[i] = *(const bf16x8*)(&As[buf][r * QBK + (((s << 2) | fq) ^ (r & 7)) * 8]);
      }
#pragma unroll
      for (int j = 0; j < 4; ++j) {
        const int r = wn * 64 + j * 16 + fr;
        bf[j] = *(const bf16x8*)(&Bs[buf][r * QBK + (((s << 2) | fq) ^ (r & 7)) * 8]);
      }
#pragma unroll
      for (int i = 0; i < 8; ++i)
#pragma unroll
        for (int j = 0; j < 4; ++j)
          acc[i][j] = __builtin_amdgcn_mfma_f32_16x16x32_bf16(af[i], bf[j], acc[i][j], 0, 0, 0);
    }
    __builtin_amdgcn_s_setprio(0);
    __builtin_amdgcn_sched_barrier(0);
    __builtin_amdgcn_s_barrier();
    if (t + 2 < nt) {
      STAGE256(t + 2, buf);
      asm volatile("s_waitcnt vmcnt(8)" ::: "memory");
    } else {
      asm volatile("s_waitcnt vmcnt(0)" ::: "memory");
    }
    __builtin_amdgcn_s_barrier();
    __builtin_amdgcn_sched_barrier(0);
  }

  if constexpr (EPI == 0) {
#pragma unroll
    for (int i = 0; i < 8; ++i)
#pragma unroll
      for (int j = 0; j < 4; ++j) {
        const int col = col0 + wn * 64 + j * 16 + fr;
#pragma unroll
        for (int r = 0; r < 4; ++r) {
          const int row = row0 + wm * 128 + i * 16 + fq * 4 + r;
          C0[(size_t)row * N + col] = acc[i][j][r];
        }
      }
  } else {
    if (col0 < H_ * D_) {  // Q: f32, ld 2048
#pragma unroll
      for (int i = 0; i < 8; ++i)
#pragma unroll
        for (int j = 0; j < 4; ++j) {
          const int col = col0 + wn * 64 + j * 16 + fr;
#pragma unroll
          for (int r = 0; r < 4; ++r) {
            const int row = row0 + wm * 128 + i * 16 + fq * 4 + r;
            C0[(size_t)row * (H_ * D_) + col] = acc[i][j][r];
          }
        }
    } else if (col0 < H_ * D_ + KV_ * D_) {  // K: f32, ld 1024
#pragma unroll
      for (int i = 0; i < 8; ++i)
#pragma unroll
        for (int j = 0; j < 4; ++j) {
          const int col = col0 - H_ * D_ + wn * 64 + j * 16 + fr;
#pragma unroll
          for (int r = 0; r < 4; ++r) {
            const int row = row0 + wm * 128 + i * 16 + fq * 4 + r;
            C1[(size_t)row * (KV_ * D_) + col] = acc[i][j][r];
          }
        }
    } else {  // V^T bf16: [b*KV+kvh][d][s]
#pragma unroll
      for (int i = 0; i < 8; ++i)
#pragma unroll
        for (int j = 0; j < 4; ++j) {
          const int cc = col0 - (H_ * D_ + KV_ * D_) + wn * 64 + j * 16 + fr;
          const int kvh = cc >> 7, d = cc & 127;
          const int row = row0 + wm * 128 + i * 16 + fq * 4;
          const int b = row / S, s = row - b * S;
          unsigned short o[4] = {f2bf(acc[i][j][0]), f2bf(acc[i][j][1]),
                                 f2bf(acc[i][j][2]), f2bf(acc[i][j][3])};
          *(short4v*)(C2 + ((size_t)(b * KV_ + kvh) * D_ + d) * S + s) = *(short4v*)o;
        }
    }
  }
#undef STAGE256
}

// ------- merged per-head RMSNorm + RoPE for Q and K (r10-proven) -------
__global__ __launch_bounds__(256) void rmsnorm_rope2(
    const float* __restrict__ qsrc, const float* __restrict__ ksrc,
    unsigned short* __restrict__ qdst, unsigned short* __restrict__ kdst,
    const float* __restrict__ qw, const float* __restrict__ kw,
    const float* __restrict__ cs, const float* __restrict__ sn, int qrows) {
  int row = blockIdx.x * 4 + (threadIdx.x >> 6);
  const int lane = threadIdx.x & 63;
  const float* p; unsigned short* o16; const float* w; int nheads; float oscale;
  if (row < qrows) { p = qsrc; o16 = qdst; w = qw; nheads = H_;  oscale = SCALE_; }
  else { row -= qrows; p = ksrc; o16 = kdst; w = kw; nheads = KV_; oscale = 1.0f; }
  const float* base = p + (size_t)row * D_;
  float x1 = base[lane];
  float x2 = base[lane + 64];
  float ss = x1 * x1 + x2 * x2;
#pragma unroll
  for (int m = 32; m; m >>= 1) ss += __shfl_xor(ss, m);
  float r = rsqrtf(ss * (1.0f / 128.0f) + 1e-6f);
  const size_t sidx = (size_t)(row / nheads) * D_;
  float n1 = x1 * r * w[lane];
  float n2 = x2 * r * w[lane + 64];
  unsigned short* ob = o16 + (size_t)row * D_;
  ob[lane]      = f2bf((n1 * cs[sidx + lane]      - n2 * sn[sidx + lane])      * oscale);
  ob[lane + 64] = f2bf((n2 * cs[sidx + lane + 64] + n1 * sn[sidx + lane + 64]) * oscale);
}

// ======== bf16 MFMA causal flash attention (r8-proven structure), GQA,
//          KVBLK=128, work-balanced pairs, defer-max, XCD-grouped flat grid ========
// fid decode: kvh = fid&7 (XCD), b = (fid>>3)>>5, j = (fid>>3)&31: qpair = j&15,
// h = kvh*2 + (j>>4).  All blocks sharing a KV set land on one XCD -> L2 reuse.
__global__ __launch_bounds__(256) void flash_bf16(
    const unsigned short* __restrict__ Qb, const unsigned short* __restrict__ Kb,
    const unsigned short* __restrict__ Vt, unsigned short* __restrict__ O,
    int S, int nqt) {
  __shared__ unsigned short Kt[128 * 128];    // [kv][d], chunk-swizzled, 32 KB
  __shared__ unsigned short Vs[128 * 128];    // [d][kv], chunk-swizzled, 32 KB
  __shared__ unsigned short Pl[4][16 * 128];  // per-wave P, swizzled, 4 KB each
  const int fid = blockIdx.x;
  const int kvh = fid & 7;
  const int rest = fid >> 3;
  const int b = rest >> 5;
  const int j = rest & 31;
  const int qpair = j & 15;
  const int h = kvh * 2 + (j >> 4);
  const int tid = threadIdx.x, w = tid >> 6, lane = tid & 63;
  const int fr = lane & 15, fq = lane >> 4;
  const int rl = lane >> 4;                   // staging row-within-4
  const int sch = lane & 15;                  // staging chunk 0..15
  const unsigned short* vhead = Vt + (size_t)(b * KV_ + kvh) * D_ * S;

#pragma unroll 1
  for (int half = 0; half < 2; ++half) {
    const int qt = half ? (nqt - 1 - qpair) : qpair;
    const int q0 = qt * 64;
    const int nkt = (q0 + 64 + 127) >> 7;     // KV-tiles of 128 covering kv <= q0+63

    bf16x8 qf[4];
    {
      const unsigned short* qp =
          Qb + ((size_t)(b * S + q0 + w * 16 + fr) * H_ + h) * D_;
#pragma unroll
      for (int s = 0; s < 4; ++s) qf[s] = *(const bf16x8*)(qp + s * 32 + fq * 8);
    }

    f32x4 acco[8] = {};   // O[q=fq*4+r][d=16c+fr]
    float mrow[4] = {-1e30f, -1e30f, -1e30f, -1e30f};
    float lrow[4] = {0.f, 0.f, 0.f, 0.f};

#pragma unroll 1
    for (int kt = 0; kt < nkt; ++kt) {
      __syncthreads();
#pragma unroll
      for (int p = 0; p < 8; ++p) {
        const int r = p * 16 + w * 4 + rl;
        const int gch = (sch & 8) | ((sch ^ r) & 7);
        GLDS16(Kb + ((size_t)(b * S + kt * 128 + r) * KV_ + kvh) * D_ + gch * 8,
               Kt + (p * 16 + w * 4) * 128);
        GLDS16(vhead + (size_t)r * S + kt * 128 + gch * 8,
               Vs + (p * 16 + w * 4) * 128);
      }
      __syncthreads();

      // ---- S = Q @ K^T (C: row=q=fq*4+r, col=kv=16t+fr); Q pre-scaled ----
      f32x4 sa[8];
      __builtin_amdgcn_s_setprio(1);
#pragma unroll
      for (int t = 0; t < 8; ++t) {
        f32x4 a = {};
        const int kv = 16 * t + fr;
#pragma unroll
        for (int s = 0; s < 4; ++s) {
          const int ch = 4 * s + fq;
          const int chs = (ch & 8) | ((ch ^ kv) & 7);
          bf16x8 kf = *(const bf16x8*)(Kt + kv * 128 + chs * 8);
          a = __builtin_amdgcn_mfma_f32_16x16x32_bf16(qf[s], kf, a, 0, 0, 0);
        }
        sa[t] = a;
      }
      __builtin_amdgcn_s_setprio(0);

      // causal mask on the last tile (global indices)
      if (kt == nkt - 1) {
#pragma unroll
        for (int t = 0; t < 8; ++t) {
          const int kvg = kt * 128 + 16 * t + fr;
#pragma unroll
          for (int r = 0; r < 4; ++r)
            if (kvg > q0 + w * 16 + fq * 4 + r) sa[t][r] = -1e30f;
        }
      }

      // ---- online softmax with defer-max (THR=8; r10-proven pattern) ----
      float mx[4];
#pragma unroll
      for (int r = 0; r < 4; ++r) {
        float m = sa[0][r];
#pragma unroll
        for (int t = 1; t < 8; ++t) m = fmaxf(m, sa[t][r]);
        m = fmaxf(m, __shfl_xor(m, 1));
        m = fmaxf(m, __shfl_xor(m, 2));
        m = fmaxf(m, __shfl_xor(m, 4));
        m = fmaxf(m, __shfl_xor(m, 8));
        mx[r] = m;
      }
      const bool nogrow = (mx[0] <= mrow[0] + 8.f) & (mx[1] <= mrow[1] + 8.f) &
                          (mx[2] <= mrow[2] + 8.f) & (mx[3] <= mrow[3] + 8.f);
      if (__all(nogrow)) {
#pragma unroll
        for (int r = 0; r < 4; ++r) {
          float sum = 0.f;
#pragma unroll
          for (int t = 0; t < 8; ++t) {
            const float pv = __expf(sa[t][r] - mrow[r]);
            sa[t][r] = pv;
            sum += pv;
          }
          sum += __shfl_xor(sum, 1);
          sum += __shfl_xor(sum, 2);
          sum += __shfl_xor(sum, 4);
          sum += __shfl_xor(sum, 8);
          lrow[r] += sum;
        }
      } else {
#pragma unroll
        for (int r = 0; r < 4; ++r) {
          const float mn = fmaxf(mrow[r], mx[r]);
          const float al = __expf(mrow[r] - mn);
          mrow[r] = mn;
          float sum = 0.f;
#pragma unroll
          for (int t = 0; t < 8; ++t) {
            const float pv = __expf(sa[t][r] - mn);
            sa[t][r] = pv;
            sum += pv;
          }
          sum += __shfl_xor(sum, 1);
          sum += __shfl_xor(sum, 2);
          sum += __shfl_xor(sum, 4);
          sum += __shfl_xor(sum, 8);
          lrow[r] = lrow[r] * al + sum;
#pragma unroll
          for (int c = 0; c < 8; ++c) acco[c][r] *= al;
        }
      }

      // ---- P -> per-wave LDS (bf16, chunk-swizzled) ----
      unsigned short* pw = &Pl[w][0];
#pragma unroll
      for (int t = 0; t < 8; ++t) {
        const int kv = 16 * t + fr;
        const int ch = kv >> 3;
#pragma unroll
        for (int r = 0; r < 4; ++r) {
          const int q = fq * 4 + r;
          pw[q * 128 + ((ch & 8) | ((ch ^ q) & 7)) * 8 + (kv & 7)] = f2bf(sa[t][r]);
        }
      }

      // ---- O += P @ V ----
      bf16x8 pf[4];
#pragma unroll
      for (int s = 0; s < 4; ++s) {
        const int ch = 4 * s + fq;
        pf[s] = *(const bf16x8*)(pw + fr * 128 + ((ch & 8) | ((ch ^ fr) & 7)) * 8);
      }
      __builtin_amdgcn_s_setprio(1);
#pragma unroll
      for (int c = 0; c < 8; ++c) {
        const int d = 16 * c + fr;
#pragma unroll
        for (int s = 0; s < 4; ++s) {
          const int ch = 4 * s + fq;
          bf16x8 vf = *(const bf16x8*)(Vs + d * 128 + ((ch & 8) | ((ch ^ d) & 7)) * 8);
          acco[c] = __builtin_amdgcn_mfma_f32_16x16x32_bf16(pf[s], vf, acco[c], 0, 0, 0);
        }
      }
      __builtin_amdgcn_s_setprio(0);
    }

    // ---- epilogue: O = acc / l, bf16 ----
    float inv[4];
#pragma unroll
    for (int r = 0; r < 4; ++r) inv[r] = 1.0f / lrow[r];
#pragma unroll
    for (int c = 0; c < 8; ++c) {
#pragma unroll
      for (int r = 0; r < 4; ++r) {
        const int q = q0 + w * 16 + fq * 4 + r;
        O[(size_t)(b * S + q) * (H_ * D_) + h * D_ + 16 * c + fr] =
            f2bf(acco[c][r] * inv[r]);
      }
    }
  }
}

extern "C" void kernel_launch(void* const* d_in, const int* in_sizes, int n_in,
                              void* d_out, int out_size, void* d_ws, size_t ws_size,
                              hipStream_t stream) {
  const float* x  = (const float*)d_in[0];
  const float* sn = (const float*)d_in[1];   // sin
  const float* cs = (const float*)d_in[2];   // cos
  // d_in[3] = attention_mask: causal, applied analytically -> unused
  const float* Wq = (const float*)d_in[4];
  const float* Wk = (const float*)d_in[5];
  const float* Wv = (const float*)d_in[6];
  const float* Wo = (const float*)d_in[7];
  const float* qw = (const float*)d_in[8];
  const float* kw = (const float*)d_in[9];
  float* out = (float*)d_out;

  const int BS = in_sizes[0] / HID_;   // B*S = 4096
  const int S  = in_sizes[3] / BS;     // 2048
  const int B  = BS / S;

  // workspace layout (88 MB total)
  float* kbuf = (float*)d_ws;                                  // BS*KV*D f32  16 MB
  unsigned short* vt   = (unsigned short*)(kbuf + (size_t)BS * KV_ * D_);  // 8 MB
  unsigned short* xb   = vt + (size_t)BS * KV_ * D_;           // BS*HID bf16  16 MB
  unsigned short* wT   = xb + (size_t)BS * HID_;               // 4096x2048 bf16 16 MB
  unsigned short* wTo  = wT + (size_t)NQKV_ * HID_;            // 2048x2048 bf16  8 MB
  unsigned short* qb   = wTo + (size_t)HID_ * (H_ * D_);       // BS*H*D bf16  16 MB
  unsigned short* kb16 = qb + (size_t)BS * H_ * D_;            // BS*KV*D bf16  8 MB
  unsigned short* ab16 = xb;                                   // reuse xb after QKV GEMM

  dim3 blk(256);

  // merged prep: x->bf16, QKV weight transpose, Wo weight transpose
  prep_all<<<dim3(16384), blk, 0, stream>>>(x, xb, Wq, Wk, Wv, wT, Wo, wTo);

  // fused QKV GEMM (256^2 pipelined + XCD swizzle): Q f32 -> d_out, K f32 -> kbuf, V^T bf16 -> vt
  gemm256<1><<<dim3(NQKV_ / QBN, BS / QBM), dim3(512), 0, stream>>>(
      xb, wT, out, kbuf, vt, BS, NQKV_, HID_, S);

  // merged per-head RMSNorm + RoPE -> bf16 (SCALE folded into Q)
  rmsnorm_rope2<<<dim3((BS * H_ + BS * KV_) / 4), blk, 0, stream>>>(
      out, kbuf, qb, kb16, qw, kw, cs, sn, BS * H_);

  // causal MFMA flash attention (KVBLK=128, XCD-grouped, defer-max) -> bf16
  flash_bf16<<<dim3((S / 128) * H_ * B), blk, 0, stream>>>(qb, kb16, vt, ab16, S, S / 64);

  // Out = abuf @ Wo (f32 into d_out)
  gemm256<0><<<dim3(HID_ / QBN, BS / QBM), dim3(512), 0, stream>>>(
      ab16, wTo, out, nullptr, nullptr, BS, HID_, HID_, S);
}